// Round 1
// baseline (784.820 us; speedup 1.0000x reference)
//
#include <hip/hip_runtime.h>
#include <cstdint>
#include <cstddef>

#define IN_DIM 512
#define OUT_DIM 256
#define OUT4 64
#define SCALE 1.8f
#define BM 64
#define KC 16

// ---------------- edge dtype probe: int64 edge_index has all-zero high words
__global__ void detect_kernel(const int* __restrict__ ei, int* __restrict__ flag) {
    int t = threadIdx.x;                       // 64 threads, one wave
    int nz = (ei[2 * t + 1] != 0) ? 1 : 0;
    unsigned long long b = __ballot(nz);
    if (t == 0) *flag = (b == 0ULL) ? 1 : 0;   // 1 => int64
}

__global__ void zero_i32(int* __restrict__ p, int n) {
    int i = blockIdx.x * blockDim.x + threadIdx.x;
    if (i < n) p[i] = 0;
}

// Wt[k][c] = W[c][k]   (coalesced read of W, scattered write; 0.5 MB total)
__global__ void transpose_w(const float* __restrict__ W, float* __restrict__ Wt) {
    int tid = blockIdx.x * blockDim.x + threadIdx.x;
    if (tid < OUT_DIM * IN_DIM) {
        int c = tid / IN_DIM, k = tid % IN_DIM;
        Wt[k * OUT_DIM + c] = W[tid];
    }
}

__global__ void count_kernel(const int* __restrict__ ei32, const long long* __restrict__ ei64,
                             const int* __restrict__ flag, int* __restrict__ cnt, int E) {
    bool w64 = (*flag != 0);
    int stride = gridDim.x * blockDim.x;
    for (int e = blockIdx.x * blockDim.x + threadIdx.x; e < E; e += stride) {
        int d = w64 ? (int)ei64[(size_t)E + e] : ei32[(size_t)E + e];
        atomicAdd(&cnt[d], 1);
    }
}

__global__ void dis_kernel(const int* __restrict__ cnt, float* __restrict__ dis, int N) {
    int i = blockIdx.x * blockDim.x + threadIdx.x;
    if (i < N) dis[i] = 1.0f / sqrtf((float)(cnt[i] + 1));   // +1 self-loop
}

// Hillis-Steele inclusive scan per 256-block
__global__ void scan1_kernel(const int* __restrict__ cnt, int* __restrict__ tmp,
                             int* __restrict__ bsum, int N) {
    __shared__ int s[256];
    int t = threadIdx.x;
    int i = blockIdx.x * 256 + t;
    s[t] = (i < N) ? cnt[i] : 0;
    __syncthreads();
    for (int off = 1; off < 256; off <<= 1) {
        int add = (t >= off) ? s[t - off] : 0;
        __syncthreads();
        s[t] += add;
        __syncthreads();
    }
    if (i < N) tmp[i] = s[t];
    if (t == 255) bsum[blockIdx.x] = s[255];
}

__global__ void scan2_kernel(const int* __restrict__ bsum, int* __restrict__ bscan, int NB) {
    __shared__ int s[256];
    int t = threadIdx.x;
    s[t] = (t < NB) ? bsum[t] : 0;
    __syncthreads();
    for (int off = 1; off < 256; off <<= 1) {
        int add = (t >= off) ? s[t - off] : 0;
        __syncthreads();
        s[t] += add;
        __syncthreads();
    }
    bscan[t] = s[t];
}

__global__ void finalize_kernel(const int* __restrict__ tmp, const int* __restrict__ bscan,
                                const int* __restrict__ cnt, int* __restrict__ rowptr,
                                int* __restrict__ cursor, int N) {
    int i = blockIdx.x * blockDim.x + threadIdx.x;
    if (i < N) {
        int base = (i >= 256) ? bscan[(i >> 8) - 1] : 0;
        int endv = tmp[i] + base;
        rowptr[i + 1] = endv;
        cursor[i] = endv - cnt[i];
        if (i == 0) rowptr[0] = 0;
    }
}

__global__ void fill_kernel(const int* __restrict__ ei32, const long long* __restrict__ ei64,
                            const int* __restrict__ flag, int* __restrict__ cursor,
                            int* __restrict__ col, int E) {
    bool w64 = (*flag != 0);
    int stride = gridDim.x * blockDim.x;
    for (int e = blockIdx.x * blockDim.x + threadIdx.x; e < E; e += stride) {
        int s, d;
        if (w64) { s = (int)ei64[e]; d = (int)ei64[(size_t)E + e]; }
        else     { s = ei32[e];      d = ei32[(size_t)E + e]; }
        int pos = atomicAdd(&cursor[d], 1);
        col[pos] = s;
    }
}

// z = x@Wt + b, row-L2-normalize, *1.8*dis[row] -> y.   64x256 tile, 256 thr,
// micro-tile 8 rows x 8 cols per thread. A-reads are wave-uniform broadcasts.
__global__ __launch_bounds__(256, 2) void gemm_norm_kernel(
    const float* __restrict__ x, const float* __restrict__ Wt,
    const float* __restrict__ bias, const float* __restrict__ dis,
    float* __restrict__ y, int N)
{
    __shared__ __align__(16) float As[BM][20];    // pad 16->20: b128-aligned rows
    __shared__ __align__(16) float Bs[KC][260];   // pad 256->260
    const int tid = threadIdx.x;
    const int row0 = blockIdx.x * BM;
    const int tc = tid & 31;     // cols 8*tc .. 8*tc+7
    const int tr = tid >> 5;     // rows tr + 8*i, i<8

    float acc[8][8];
#pragma unroll
    for (int i = 0; i < 8; ++i)
#pragma unroll
        for (int j = 0; j < 8; ++j) acc[i][j] = 0.f;

    for (int k0 = 0; k0 < IN_DIM; k0 += KC) {
        {   // stage A: 64x16 floats, one float4 per thread
            int r = tid >> 2, kq = tid & 3;
            int grow = row0 + r;
            float4 v = make_float4(0.f, 0.f, 0.f, 0.f);
            if (grow < N) v = *(const float4*)&x[(size_t)grow * IN_DIM + k0 + 4 * kq];
            *(float4*)&As[r][4 * kq] = v;
        }
#pragma unroll
        for (int ii = 0; ii < 4; ++ii) {   // stage B: 16x256 floats, coalesced from Wt
            int fidx = tid + 256 * ii;
            int kk = fidx >> 6, c4 = fidx & 63;
            float4 v = *(const float4*)&Wt[(size_t)(k0 + kk) * OUT_DIM + 4 * c4];
            *(float4*)&Bs[kk][4 * c4] = v;
        }
        __syncthreads();
#pragma unroll
        for (int kk4 = 0; kk4 < KC / 4; ++kk4) {
            float4 b0[4], b1[4];
#pragma unroll
            for (int kk = 0; kk < 4; ++kk) {
                b0[kk] = *(const float4*)&Bs[kk4 * 4 + kk][tc * 8];
                b1[kk] = *(const float4*)&Bs[kk4 * 4 + kk][tc * 8 + 4];
            }
#pragma unroll
            for (int i = 0; i < 8; ++i) {
                float4 a = *(const float4*)&As[tr + 8 * i][kk4 * 4];
                float av[4] = {a.x, a.y, a.z, a.w};
#pragma unroll
                for (int kk = 0; kk < 4; ++kk) {
                    acc[i][0] = fmaf(av[kk], b0[kk].x, acc[i][0]);
                    acc[i][1] = fmaf(av[kk], b0[kk].y, acc[i][1]);
                    acc[i][2] = fmaf(av[kk], b0[kk].z, acc[i][2]);
                    acc[i][3] = fmaf(av[kk], b0[kk].w, acc[i][3]);
                    acc[i][4] = fmaf(av[kk], b1[kk].x, acc[i][4]);
                    acc[i][5] = fmaf(av[kk], b1[kk].y, acc[i][5]);
                    acc[i][6] = fmaf(av[kk], b1[kk].z, acc[i][6]);
                    acc[i][7] = fmaf(av[kk], b1[kk].w, acc[i][7]);
                }
            }
        }
        __syncthreads();
    }

    // epilogue: +bias, row L2 norm (reduce over 32 lanes = the tc group), scale, store
    float4 bv0 = *(const float4*)&bias[tc * 8];
    float4 bv1 = *(const float4*)&bias[tc * 8 + 4];
    float bb[8] = {bv0.x, bv0.y, bv0.z, bv0.w, bv1.x, bv1.y, bv1.z, bv1.w};
#pragma unroll
    for (int i = 0; i < 8; ++i) {
        int row = row0 + tr + 8 * i;
#pragma unroll
        for (int j = 0; j < 8; ++j) acc[i][j] += bb[j];
        float ss = 0.f;
#pragma unroll
        for (int j = 0; j < 8; ++j) ss = fmaf(acc[i][j], acc[i][j], ss);
#pragma unroll
        for (int m = 16; m >= 1; m >>= 1) ss += __shfl_xor(ss, m);  // within 32-lane half
        if (row < N) {
            float nrm = sqrtf(ss);
            float sc = SCALE * dis[row] / fmaxf(nrm, 1e-12f);
            float4 o0, o1;
            o0.x = acc[i][0] * sc; o0.y = acc[i][1] * sc;
            o0.z = acc[i][2] * sc; o0.w = acc[i][3] * sc;
            o1.x = acc[i][4] * sc; o1.y = acc[i][5] * sc;
            o1.z = acc[i][6] * sc; o1.w = acc[i][7] * sc;
            *(float4*)&y[(size_t)row * OUT_DIM + tc * 8] = o0;
            *(float4*)&y[(size_t)row * OUT_DIM + tc * 8 + 4] = o1;
        }
    }
}

// one wave per node: acc = y[n] + sum over in-edges y[src]; out = dis[n]*acc
__global__ __launch_bounds__(256) void gather_kernel(
    const float4* __restrict__ y4, const int* __restrict__ rowptr,
    const int* __restrict__ col, const float* __restrict__ dis,
    float4* __restrict__ out4, int N)
{
    const int lane = threadIdx.x & 63;
    const int wid = (blockIdx.x * blockDim.x + threadIdx.x) >> 6;
    const int nw = (gridDim.x * blockDim.x) >> 6;
    for (int n = wid; n < N; n += nw) {
        const int beg = rowptr[n], end = rowptr[n + 1];
        float4 acc = y4[(size_t)n * OUT4 + lane];   // self-loop term
        int j = beg;
        for (; j + 1 < end; j += 2) {
            int s0 = col[j], s1 = col[j + 1];
            float4 v0 = y4[(size_t)s0 * OUT4 + lane];
            float4 v1 = y4[(size_t)s1 * OUT4 + lane];
            acc.x += v0.x + v1.x; acc.y += v0.y + v1.y;
            acc.z += v0.z + v1.z; acc.w += v0.w + v1.w;
        }
        if (j < end) {
            int s = col[j];
            float4 v = y4[(size_t)s * OUT4 + lane];
            acc.x += v.x; acc.y += v.y; acc.z += v.z; acc.w += v.w;
        }
        float dn = dis[n];
        float4 o;
        o.x = acc.x * dn; o.y = acc.y * dn; o.z = acc.z * dn; o.w = acc.w * dn;
        out4[(size_t)n * OUT4 + lane] = o;
    }
}

extern "C" void kernel_launch(void* const* d_in, const int* in_sizes, int n_in,
                              void* d_out, int out_size, void* d_ws, size_t ws_size,
                              hipStream_t stream) {
    const float* x = (const float*)d_in[0];
    const float* W = (const float*)d_in[1];
    const float* b = (const float*)d_in[2];
    const int* ei32 = (const int*)d_in[3];
    const long long* ei64 = (const long long*)d_in[3];
    const int N = in_sizes[0] / IN_DIM;
    const int E = in_sizes[3] / 2;
    float* out = (float*)d_out;

    char* ws = (char*)d_ws;
    size_t off = 0;
    auto alloc = [&](size_t bytes) -> void* {
        void* p = ws + off;
        off = (off + bytes + 255) & ~(size_t)255;
        return p;
    };
    float* y      = (float*)alloc((size_t)N * OUT_DIM * sizeof(float)); // 51.2 MB
    float* Wt     = (float*)alloc((size_t)IN_DIM * OUT_DIM * sizeof(float));
    float* dis    = (float*)alloc((size_t)N * sizeof(float));
    int*   cnt    = (int*)alloc((size_t)N * sizeof(int));
    int*   tmp    = (int*)alloc((size_t)N * sizeof(int));
    int*   rowptr = (int*)alloc((size_t)(N + 1) * sizeof(int));
    int*   cursor = (int*)alloc((size_t)N * sizeof(int));
    int*   bsum   = (int*)alloc(512 * sizeof(int));
    int*   bscan  = (int*)alloc(512 * sizeof(int));
    int*   flag   = (int*)alloc(sizeof(int));
    int*   col    = (int*)alloc((size_t)E * sizeof(int));               // 6.4 MB
    (void)ws_size; (void)n_in; (void)out_size;

    const int NB = (N + 255) >> 8;

    hipLaunchKernelGGL(detect_kernel, dim3(1), dim3(64), 0, stream, ei32, flag);
    hipLaunchKernelGGL(zero_i32, dim3((N + 255) / 256), dim3(256), 0, stream, cnt, N);
    hipLaunchKernelGGL(transpose_w, dim3((OUT_DIM * IN_DIM + 255) / 256), dim3(256), 0, stream, W, Wt);
    hipLaunchKernelGGL(count_kernel, dim3(2048), dim3(256), 0, stream, ei32, ei64, flag, cnt, E);
    hipLaunchKernelGGL(dis_kernel, dim3((N + 255) / 256), dim3(256), 0, stream, cnt, dis, N);
    hipLaunchKernelGGL(scan1_kernel, dim3(NB), dim3(256), 0, stream, cnt, tmp, bsum, N);
    hipLaunchKernelGGL(scan2_kernel, dim3(1), dim3(256), 0, stream, bsum, bscan, NB);
    hipLaunchKernelGGL(finalize_kernel, dim3((N + 255) / 256), dim3(256), 0, stream, tmp, bscan, cnt, rowptr, cursor, N);
    hipLaunchKernelGGL(fill_kernel, dim3(2048), dim3(256), 0, stream, ei32, ei64, flag, cursor, col, E);
    hipLaunchKernelGGL(gemm_norm_kernel, dim3((N + BM - 1) / BM), dim3(256), 0, stream, x, Wt, b, dis, y, N);
    hipLaunchKernelGGL(gather_kernel, dim3(2048), dim3(256), 0, stream, (const float4*)y, rowptr, col, dis, (float4*)out, N);
}

// Round 5
// 640.430 us; speedup vs baseline: 1.2255x; 1.2255x over previous
//
#include <hip/hip_runtime.h>
#include <cstdint>
#include <cstddef>

#define IN_DIM 512
#define OUT_DIM 256
#define SCALE 1.8f

typedef __bf16 bf16x8 __attribute__((ext_vector_type(8)));
typedef float f32x4 __attribute__((ext_vector_type(4)));

__device__ __forceinline__ float bf_lo(unsigned u) { return __uint_as_float(u << 16); }
__device__ __forceinline__ float bf_hi(unsigned u) { return __uint_as_float(u & 0xffff0000u); }

// ---------------- edge dtype probe: int64 edge_index has all-zero high words
__global__ void detect_kernel(const int* __restrict__ ei, int* __restrict__ flag) {
    int t = threadIdx.x;                       // 64 threads, one wave
    int nz = (ei[2 * t + 1] != 0) ? 1 : 0;
    unsigned long long b = __ballot(nz);
    if (t == 0) *flag = (b == 0ULL) ? 1 : 0;   // 1 => int64
}

__global__ void zero_i32(int* __restrict__ p, int n) {
    int i = blockIdx.x * blockDim.x + threadIdx.x;
    if (i < n) p[i] = 0;
}

// Split W (fp32 [256][512]) into bf16 hi/lo in MFMA B-fragment order:
// slot(k0,nt,lane) holds W[nt*16 + (lane&15)][k0*32 + (lane>>4)*8 .. +7]
__global__ void convert_w(const float* __restrict__ W, __bf16* __restrict__ Bh,
                          __bf16* __restrict__ Bl) {
    int t = blockIdx.x * blockDim.x + threadIdx.x;       // one per 8-elem chunk
    if (t >= OUT_DIM * (IN_DIM / 8)) return;
    int n = t >> 6, kc = t & 63;                         // 64 chunks per row
    float4 p0 = *(const float4*)&W[(size_t)n * IN_DIM + kc * 8];
    float4 p1 = *(const float4*)&W[(size_t)n * IN_DIM + kc * 8 + 4];
    float v[8] = {p0.x, p0.y, p0.z, p0.w, p1.x, p1.y, p1.z, p1.w};
    int nt = n >> 4, k0 = kc >> 2;
    int lane = ((kc & 3) << 4) | (n & 15);
    size_t slot = ((size_t)(k0 * 16 + nt) * 64 + lane) * 8;
    bf16x8 hv, lv;
#pragma unroll
    for (int j = 0; j < 8; ++j) {
        __bf16 h = (__bf16)v[j];
        hv[j] = h;
        lv[j] = (__bf16)(v[j] - (float)h);
    }
    *(bf16x8*)&Bh[slot] = hv;
    *(bf16x8*)&Bl[slot] = lv;
}

__global__ void count_kernel(const int* __restrict__ ei32, const long long* __restrict__ ei64,
                             const int* __restrict__ flag, int* __restrict__ cnt, int E) {
    bool w64 = (*flag != 0);
    int stride = gridDim.x * blockDim.x;
    for (int e = blockIdx.x * blockDim.x + threadIdx.x; e < E; e += stride) {
        int d = w64 ? (int)ei64[(size_t)E + e] : ei32[(size_t)E + e];
        atomicAdd(&cnt[d], 1);
    }
}

__global__ void dis_kernel(const int* __restrict__ cnt, float* __restrict__ dis, int N) {
    int i = blockIdx.x * blockDim.x + threadIdx.x;
    if (i < N) dis[i] = 1.0f / sqrtf((float)(cnt[i] + 1));   // +1 self-loop
}

// Hillis-Steele inclusive scan per 256-block
__global__ void scan1_kernel(const int* __restrict__ cnt, int* __restrict__ tmp,
                             int* __restrict__ bsum, int N) {
    __shared__ int s[256];
    int t = threadIdx.x;
    int i = blockIdx.x * 256 + t;
    s[t] = (i < N) ? cnt[i] : 0;
    __syncthreads();
    for (int off = 1; off < 256; off <<= 1) {
        int add = (t >= off) ? s[t - off] : 0;
        __syncthreads();
        s[t] += add;
        __syncthreads();
    }
    if (i < N) tmp[i] = s[t];
    if (t == 255) bsum[blockIdx.x] = s[255];
}

__global__ void scan2_kernel(const int* __restrict__ bsum, int* __restrict__ bscan, int NB) {
    __shared__ int s[256];
    int t = threadIdx.x;
    s[t] = (t < NB) ? bsum[t] : 0;
    __syncthreads();
    for (int off = 1; off < 256; off <<= 1) {
        int add = (t >= off) ? s[t - off] : 0;
        __syncthreads();
        s[t] += add;
        __syncthreads();
    }
    bscan[t] = s[t];
}

__global__ void finalize_kernel(const int* __restrict__ tmp, const int* __restrict__ bscan,
                                const int* __restrict__ cnt, int* __restrict__ rowptr,
                                int* __restrict__ cursor, int N) {
    int i = blockIdx.x * blockDim.x + threadIdx.x;
    if (i < N) {
        int base = (i >= 256) ? bscan[(i >> 8) - 1] : 0;
        int endv = tmp[i] + base;
        rowptr[i + 1] = endv;
        cursor[i] = endv - cnt[i];
        if (i == 0) rowptr[0] = 0;
    }
}

__global__ void fill_kernel(const int* __restrict__ ei32, const long long* __restrict__ ei64,
                            const int* __restrict__ flag, int* __restrict__ cursor,
                            int* __restrict__ col, int E) {
    bool w64 = (*flag != 0);
    int stride = gridDim.x * blockDim.x;
    for (int e = blockIdx.x * blockDim.x + threadIdx.x; e < E; e += stride) {
        int s, d;
        if (w64) { s = (int)ei64[e]; d = (int)ei64[(size_t)E + e]; }
        else     { s = ei32[e];      d = ei32[(size_t)E + e]; }
        int pos = atomicAdd(&cursor[d], 1);
        col[pos] = s;
    }
}

// Split-bf16 MFMA GEMM: z = x@W^T + b, row-L2-normalize, *1.8*dis[row] -> y (bf16).
// 4 waves/block, one 16-row tile per wave, full 256-col width, no LDS, no barriers.
// A fragments read directly from fp32 x (contiguous 128B per row-chunk), split
// hi/lo in-register. B fragments pre-split, pre-permuted (L2-resident, 512 KB).
__global__ __launch_bounds__(256, 2) void mfma_gemm(
    const float* __restrict__ x, const bf16x8* __restrict__ Bh8,
    const bf16x8* __restrict__ Bl8, const float* __restrict__ bias,
    const float* __restrict__ dis, __bf16* __restrict__ y, int Nn, int MT)
{
    const int lane = threadIdx.x & 63;
    const int rt = blockIdx.x * 4 + (threadIdx.x >> 6);
    if (rt >= MT) return;

    f32x4 acc[16];
#pragma unroll
    for (int nt = 0; nt < 16; ++nt) acc[nt] = (f32x4){0.f, 0.f, 0.f, 0.f};

    const int row = rt * 16 + (lane & 15);
    // clamp OOB rows to row 0 (their garbage result is never stored)
    const float* xp = x + (size_t)(row < Nn ? row : 0) * IN_DIM + ((lane >> 4) * 8);

#pragma unroll 2
    for (int k0 = 0; k0 < 16; ++k0) {
        float4 p0 = *(const float4*)(xp + k0 * 32);
        float4 p1 = *(const float4*)(xp + k0 * 32 + 4);
        float av[8] = {p0.x, p0.y, p0.z, p0.w, p1.x, p1.y, p1.z, p1.w};
        bf16x8 ah, al;
#pragma unroll
        for (int j = 0; j < 8; ++j) {
            __bf16 h = (__bf16)av[j];
            ah[j] = h;
            al[j] = (__bf16)(av[j] - (float)h);
        }
        const bf16x8* bh = Bh8 + (size_t)(k0 * 16) * 64 + lane;
        const bf16x8* bl = Bl8 + (size_t)(k0 * 16) * 64 + lane;
#pragma unroll
        for (int nt = 0; nt < 16; ++nt) {
            bf16x8 vh = bh[nt * 64];
            bf16x8 vl = bl[nt * 64];
            acc[nt] = __builtin_amdgcn_mfma_f32_16x16x32_bf16(ah, vh, acc[nt], 0, 0, 0);
            acc[nt] = __builtin_amdgcn_mfma_f32_16x16x32_bf16(al, vh, acc[nt], 0, 0, 0);
            acc[nt] = __builtin_amdgcn_mfma_f32_16x16x32_bf16(ah, vl, acc[nt], 0, 0, 0);
        }
    }

    // epilogue: +bias, row sum-of-squares (16-lane butterfly), scale, bf16 store
    // D layout: col = nt*16 + (lane&15), row = rt*16 + (lane>>4)*4 + reg
    const int col0 = lane & 15;
    float ss[4] = {0.f, 0.f, 0.f, 0.f};
#pragma unroll
    for (int nt = 0; nt < 16; ++nt) {
        float bb = bias[nt * 16 + col0];
#pragma unroll
        for (int j = 0; j < 4; ++j) {
            acc[nt][j] += bb;
            ss[j] = fmaf(acc[nt][j], acc[nt][j], ss[j]);
        }
    }
#pragma unroll
    for (int m = 1; m <= 8; m <<= 1) {
#pragma unroll
        for (int j = 0; j < 4; ++j) ss[j] += __shfl_xor(ss[j], m);
    }
    const int rbase = rt * 16 + (lane >> 4) * 4;
#pragma unroll
    for (int j = 0; j < 4; ++j) {
        int r = rbase + j;
        if (r < Nn) {
            float sc = SCALE * dis[r] / fmaxf(sqrtf(ss[j]), 1e-12f);
#pragma unroll
            for (int nt = 0; nt < 16; ++nt)
                y[(size_t)r * OUT_DIM + nt * 16 + col0] = (__bf16)(acc[nt][j] * sc);
        }
    }
}

// one wave per node: acc = y[n] + sum over in-edges y[src] (bf16 rows, 512B each);
// out = dis[n]*acc (fp32)
__global__ __launch_bounds__(256) void gather_kernel(
    const uint2* __restrict__ y2, const int* __restrict__ rowptr,
    const int* __restrict__ col, const float* __restrict__ dis,
    float4* __restrict__ out4, int Nn)
{
    const int lane = threadIdx.x & 63;
    const int wid = (blockIdx.x * blockDim.x + threadIdx.x) >> 6;
    const int nw = (gridDim.x * blockDim.x) >> 6;
    for (int n = wid; n < Nn; n += nw) {
        const int beg = rowptr[n], end = rowptr[n + 1];
        uint2 v = y2[(size_t)n * 64 + lane];            // self-loop term
        float a0 = bf_lo(v.x), a1 = bf_hi(v.x), a2 = bf_lo(v.y), a3 = bf_hi(v.y);
        int j = beg;
        for (; j + 1 < end; j += 2) {
            int s0 = col[j], s1 = col[j + 1];
            uint2 u0 = y2[(size_t)s0 * 64 + lane];
            uint2 u1 = y2[(size_t)s1 * 64 + lane];
            a0 += bf_lo(u0.x) + bf_lo(u1.x);
            a1 += bf_hi(u0.x) + bf_hi(u1.x);
            a2 += bf_lo(u0.y) + bf_lo(u1.y);
            a3 += bf_hi(u0.y) + bf_hi(u1.y);
        }
        if (j < end) {
            uint2 u = y2[(size_t)col[j] * 64 + lane];
            a0 += bf_lo(u.x); a1 += bf_hi(u.x);
            a2 += bf_lo(u.y); a3 += bf_hi(u.y);
        }
        float dn = dis[n];
        out4[(size_t)n * 64 + lane] = make_float4(a0 * dn, a1 * dn, a2 * dn, a3 * dn);
    }
}

extern "C" void kernel_launch(void* const* d_in, const int* in_sizes, int n_in,
                              void* d_out, int out_size, void* d_ws, size_t ws_size,
                              hipStream_t stream) {
    const float* x = (const float*)d_in[0];
    const float* W = (const float*)d_in[1];
    const float* b = (const float*)d_in[2];
    const int* ei32 = (const int*)d_in[3];
    const long long* ei64 = (const long long*)d_in[3];
    const int N = in_sizes[0] / IN_DIM;
    const int E = in_sizes[3] / 2;
    const int MT = (N + 15) / 16;     // 16-row tiles
    float* out = (float*)d_out;

    char* ws = (char*)d_ws;
    size_t off = 0;
    auto alloc = [&](size_t bytes) -> void* {
        void* p = ws + off;
        off = (off + bytes + 255) & ~(size_t)255;
        return p;
    };
    __bf16* y    = (__bf16*)alloc((size_t)MT * 16 * OUT_DIM * sizeof(__bf16)); // 25.6 MB
    __bf16* Bh   = (__bf16*)alloc((size_t)IN_DIM * OUT_DIM * sizeof(__bf16));  // 256 KB
    __bf16* Bl   = (__bf16*)alloc((size_t)IN_DIM * OUT_DIM * sizeof(__bf16));
    float* dis   = (float*)alloc((size_t)N * sizeof(float));
    int*   cnt   = (int*)alloc((size_t)N * sizeof(int));
    int*   tmp   = (int*)alloc((size_t)N * sizeof(int));
    int*   rowptr= (int*)alloc((size_t)(N + 1) * sizeof(int));
    int*   cursor= (int*)alloc((size_t)N * sizeof(int));
    int*   bsum  = (int*)alloc(512 * sizeof(int));
    int*   bscan = (int*)alloc(512 * sizeof(int));
    int*   flag  = (int*)alloc(sizeof(int));
    int*   col   = (int*)alloc((size_t)E * sizeof(int));                       // 6.4 MB
    (void)ws_size; (void)n_in; (void)out_size;

    const int NB = (N + 255) >> 8;

    hipLaunchKernelGGL(detect_kernel, dim3(1), dim3(64), 0, stream, ei32, flag);
    hipLaunchKernelGGL(zero_i32, dim3((N + 255) / 256), dim3(256), 0, stream, cnt, N);
    hipLaunchKernelGGL(convert_w, dim3((OUT_DIM * (IN_DIM / 8) + 255) / 256), dim3(256), 0, stream, W, Bh, Bl);
    hipLaunchKernelGGL(count_kernel, dim3(2048), dim3(256), 0, stream, ei32, ei64, flag, cnt, E);
    hipLaunchKernelGGL(dis_kernel, dim3((N + 255) / 256), dim3(256), 0, stream, cnt, dis, N);
    hipLaunchKernelGGL(scan1_kernel, dim3(NB), dim3(256), 0, stream, cnt, tmp, bsum, N);
    hipLaunchKernelGGL(scan2_kernel, dim3(1), dim3(256), 0, stream, bsum, bscan, NB);
    hipLaunchKernelGGL(finalize_kernel, dim3((N + 255) / 256), dim3(256), 0, stream, tmp, bscan, cnt, rowptr, cursor, N);
    hipLaunchKernelGGL(fill_kernel, dim3(2048), dim3(256), 0, stream, ei32, ei64, flag, cursor, col, E);
    hipLaunchKernelGGL(mfma_gemm, dim3((MT + 3) / 4), dim3(256), 0, stream,
                       x, (const bf16x8*)Bh, (const bf16x8*)Bl, b, dis, y, N, MT);
    hipLaunchKernelGGL(gather_kernel, dim3(2048), dim3(256), 0, stream,
                       (const uint2*)y, rowptr, col, dis, (float4*)out, N);
}

// Round 10
// 551.970 us; speedup vs baseline: 1.4219x; 1.1603x over previous
//
#include <hip/hip_runtime.h>
#include <cstdint>
#include <cstddef>

#define IN_DIM 512
#define OUT_DIM 256
#define SCALE 1.8f

typedef __bf16 bf16x8 __attribute__((ext_vector_type(8)));
typedef float f32x4 __attribute__((ext_vector_type(4)));

typedef const __attribute__((address_space(1))) unsigned int* gas1_t;
typedef __attribute__((address_space(3))) unsigned int* as3_t;

__device__ __forceinline__ void gload_lds16(const void* g, void* l) {
    // global->LDS DMA, 16B per lane; LDS dest = wave-uniform base + lane*16
    __builtin_amdgcn_global_load_lds((gas1_t)g, (as3_t)l, 16, 0, 0);
}

__device__ __forceinline__ float bf_lo(unsigned u) { return __uint_as_float(u << 16); }
__device__ __forceinline__ float bf_hi(unsigned u) { return __uint_as_float(u & 0xffff0000u); }

// ---------------- edge dtype probe: int64 edge_index has all-zero high words
__global__ void detect_kernel(const int* __restrict__ ei, int* __restrict__ flag) {
    int t = threadIdx.x;                       // 64 threads, one wave
    int nz = (ei[2 * t + 1] != 0) ? 1 : 0;
    unsigned long long b = __ballot(nz);
    if (t == 0) *flag = (b == 0ULL) ? 1 : 0;   // 1 => int64
}

__global__ void zero_i32(int* __restrict__ p, int n) {
    int i = blockIdx.x * blockDim.x + threadIdx.x;
    if (i < n) p[i] = 0;
}

// Split W (fp32 [256][512]) into bf16 hi/lo in MFMA B-fragment order:
// slot(k0,nt,lane) holds W[nt*16 + (lane&15)][k0*32 + (lane>>4)*8 .. +7]
__global__ void convert_w(const float* __restrict__ W, __bf16* __restrict__ Bh,
                          __bf16* __restrict__ Bl) {
    int t = blockIdx.x * blockDim.x + threadIdx.x;       // one per 8-elem chunk
    if (t >= OUT_DIM * (IN_DIM / 8)) return;
    int n = t >> 6, kc = t & 63;                         // 64 chunks per row
    float4 p0 = *(const float4*)&W[(size_t)n * IN_DIM + kc * 8];
    float4 p1 = *(const float4*)&W[(size_t)n * IN_DIM + kc * 8 + 4];
    float v[8] = {p0.x, p0.y, p0.z, p0.w, p1.x, p1.y, p1.z, p1.w};
    int nt = n >> 4, k0 = kc >> 2;
    int lane = ((kc & 3) << 4) | (n & 15);
    size_t slot = ((size_t)(k0 * 16 + nt) * 64 + lane) * 8;
    bf16x8 hv, lv;
#pragma unroll
    for (int j = 0; j < 8; ++j) {
        __bf16 h = (__bf16)v[j];
        hv[j] = h;
        lv[j] = (__bf16)(v[j] - (float)h);
    }
    *(bf16x8*)&Bh[slot] = hv;
    *(bf16x8*)&Bl[slot] = lv;
}

__global__ void count_kernel(const int* __restrict__ ei32, const long long* __restrict__ ei64,
                             const int* __restrict__ flag, int* __restrict__ cnt, int E) {
    bool w64 = (*flag != 0);
    int stride = gridDim.x * blockDim.x;
    for (int e = blockIdx.x * blockDim.x + threadIdx.x; e < E; e += stride) {
        int d = w64 ? (int)ei64[(size_t)E + e] : ei32[(size_t)E + e];
        atomicAdd(&cnt[d], 1);
    }
}

// Hillis-Steele inclusive scan per 256-block
__global__ void scan1_kernel(const int* __restrict__ cnt, int* __restrict__ tmp,
                             int* __restrict__ bsum, int N) {
    __shared__ int s[256];
    int t = threadIdx.x;
    int i = blockIdx.x * 256 + t;
    s[t] = (i < N) ? cnt[i] : 0;
    __syncthreads();
    for (int off = 1; off < 256; off <<= 1) {
        int add = (t >= off) ? s[t - off] : 0;
        __syncthreads();
        s[t] += add;
        __syncthreads();
    }
    if (i < N) tmp[i] = s[t];
    if (t == 255) bsum[blockIdx.x] = s[255];
}

__global__ void scan2_kernel(const int* __restrict__ bsum, int* __restrict__ bscan, int NB) {
    __shared__ int s[256];
    int t = threadIdx.x;
    s[t] = (t < NB) ? bsum[t] : 0;
    __syncthreads();
    for (int off = 1; off < 256; off <<= 1) {
        int add = (t >= off) ? s[t - off] : 0;
        __syncthreads();
        s[t] += add;
        __syncthreads();
    }
    bscan[t] = s[t];
}

// rowptr/cursor from scanned counts; also dis = rsqrt(deg+1)  (folded dis_kernel)
__global__ void finalize_kernel(const int* __restrict__ tmp, const int* __restrict__ bscan,
                                const int* __restrict__ cnt, int* __restrict__ rowptr,
                                int* __restrict__ cursor, float* __restrict__ dis, int N) {
    int i = blockIdx.x * blockDim.x + threadIdx.x;
    if (i < N) {
        int c = cnt[i];
        int base = (i >= 256) ? bscan[(i >> 8) - 1] : 0;
        int endv = tmp[i] + base;
        rowptr[i + 1] = endv;
        cursor[i] = endv - c;
        dis[i] = 1.0f / sqrtf((float)(c + 1));   // +1 self-loop
        if (i == 0) rowptr[0] = 0;
    }
}

__global__ void fill_kernel(const int* __restrict__ ei32, const long long* __restrict__ ei64,
                            const int* __restrict__ flag, int* __restrict__ cursor,
                            int* __restrict__ col, int E) {
    bool w64 = (*flag != 0);
    int stride = gridDim.x * blockDim.x;
    for (int e = blockIdx.x * blockDim.x + threadIdx.x; e < E; e += stride) {
        int s, d;
        if (w64) { s = (int)ei64[e]; d = (int)ei64[(size_t)E + e]; }
        else     { s = ei32[e];      d = ei32[(size_t)E + e]; }
        int pos = atomicAdd(&cursor[d], 1);
        col[pos] = s;
    }
}

// Split-bf16 MFMA GEMM with LDS-staged B (double-buffered).
// Block = 4 waves, 64 rows; each wave owns one 16-row tile, full 256 cols.
// Per k0 step the block stages the 32 KB B-slice (hi+lo) once into LDS via
// global_load_lds; all 4 waves consume it -> L2 B-traffic /4 vs direct reads.
__global__ __launch_bounds__(256, 2) void mfma_gemm(
    const float* __restrict__ x, const __bf16* __restrict__ Bh,
    const __bf16* __restrict__ Bl, const float* __restrict__ bias,
    const float* __restrict__ dis, __bf16* __restrict__ y, int Nn, int MT)
{
    __shared__ __align__(16) __bf16 lds[2][2][8192];   // [buf][hi/lo][slice] = 64 KB
    const int tid  = threadIdx.x;
    const int lane = tid & 63;
    const int w    = tid >> 6;                 // wave id 0..3
    const int rt   = blockIdx.x * 4 + w;       // 16-row tile (may exceed MT; no early return — barriers!)

    // stage k0-slice into buffer p: 2048 slots x 16B, 8 issues/thread
    auto stage = [&](int p, int k0) {
        const __bf16* sH = Bh + (size_t)k0 * 8192;
        const __bf16* sL = Bl + (size_t)k0 * 8192;
#pragma unroll
        for (int i = 0; i < 4; ++i) {
            int chunk = w * 4 + i;                      // 0..15, 64 slots each
            size_t goff = ((size_t)chunk * 64 + lane) * 8;
            size_t loff = (size_t)chunk * 64 * 8;       // wave-uniform LDS base
            gload_lds16(sH + goff, &lds[p][0][loff]);
            gload_lds16(sL + goff, &lds[p][1][loff]);
        }
    };

    f32x4 acc[16];
#pragma unroll
    for (int nt = 0; nt < 16; ++nt) acc[nt] = (f32x4){0.f, 0.f, 0.f, 0.f};

    const int row = rt * 16 + (lane & 15);
    // clamp OOB rows to row 0 (their garbage result is never stored)
    const float* xp = x + (size_t)(row < Nn ? row : 0) * IN_DIM + ((lane >> 4) * 8);

    stage(0, 0);
    __syncthreads();                           // drains vmcnt -> buf0 ready

    for (int k0 = 0; k0 < 16; ++k0) {
        const int p = k0 & 1;
        if (k0 < 15) stage(p ^ 1, k0 + 1);     // prefetch next slice into other buf

        float4 p0 = *(const float4*)(xp + k0 * 32);
        float4 p1 = *(const float4*)(xp + k0 * 32 + 4);
        float av[8] = {p0.x, p0.y, p0.z, p0.w, p1.x, p1.y, p1.z, p1.w};
        bf16x8 ah, al;
#pragma unroll
        for (int j = 0; j < 8; ++j) {
            __bf16 h = (__bf16)av[j];
            ah[j] = h;
            al[j] = (__bf16)(av[j] - (float)h);
        }
        const __bf16* bH = &lds[p][0][0];
        const __bf16* bL = &lds[p][1][0];
#pragma unroll
        for (int nt = 0; nt < 16; ++nt) {
            bf16x8 vh = *(const bf16x8*)(bH + (((size_t)nt * 64 + lane) << 3));
            bf16x8 vl = *(const bf16x8*)(bL + (((size_t)nt * 64 + lane) << 3));
            acc[nt] = __builtin_amdgcn_mfma_f32_16x16x32_bf16(ah, vh, acc[nt], 0, 0, 0);
            acc[nt] = __builtin_amdgcn_mfma_f32_16x16x32_bf16(al, vh, acc[nt], 0, 0, 0);
            acc[nt] = __builtin_amdgcn_mfma_f32_16x16x32_bf16(ah, vl, acc[nt], 0, 0, 0);
        }
        __syncthreads();   // all waves done with buf p; staged loads for p^1 drained
    }

    // epilogue: +bias, row sum-of-squares (16-lane butterfly), scale, bf16 store
    // D layout: col = nt*16 + (lane&15), row = rt*16 + (lane>>4)*4 + reg
    const int col0 = lane & 15;
    float ss[4] = {0.f, 0.f, 0.f, 0.f};
#pragma unroll
    for (int nt = 0; nt < 16; ++nt) {
        float bb = bias[nt * 16 + col0];
#pragma unroll
        for (int j = 0; j < 4; ++j) {
            acc[nt][j] += bb;
            ss[j] = fmaf(acc[nt][j], acc[nt][j], ss[j]);
        }
    }
#pragma unroll
    for (int m = 1; m <= 8; m <<= 1) {
#pragma unroll
        for (int j = 0; j < 4; ++j) ss[j] += __shfl_xor(ss[j], m);
    }
    const int rbase = rt * 16 + (lane >> 4) * 4;
#pragma unroll
    for (int j = 0; j < 4; ++j) {
        int r = rbase + j;
        if (r < Nn) {
            float sc = SCALE * dis[r] / fmaxf(sqrtf(ss[j]), 1e-12f);
#pragma unroll
            for (int nt = 0; nt < 16; ++nt)
                y[(size_t)r * OUT_DIM + nt * 16 + col0] = (__bf16)(acc[nt][j] * sc);
        }
    }
}

// one wave per node: acc = y[n] + sum over in-edges y[src] (bf16 rows, 512B each);
// out = dis[n]*acc (fp32)
__global__ __launch_bounds__(256) void gather_kernel(
    const uint2* __restrict__ y2, const int* __restrict__ rowptr,
    const int* __restrict__ col, const float* __restrict__ dis,
    float4* __restrict__ out4, int Nn)
{
    const int lane = threadIdx.x & 63;
    const int wid = (blockIdx.x * blockDim.x + threadIdx.x) >> 6;
    const int nw = (gridDim.x * blockDim.x) >> 6;
    for (int n = wid; n < Nn; n += nw) {
        const int beg = rowptr[n], end = rowptr[n + 1];
        uint2 v = y2[(size_t)n * 64 + lane];            // self-loop term
        float a0 = bf_lo(v.x), a1 = bf_hi(v.x), a2 = bf_lo(v.y), a3 = bf_hi(v.y);
        int j = beg;
        for (; j + 1 < end; j += 2) {
            int s0 = col[j], s1 = col[j + 1];
            uint2 u0 = y2[(size_t)s0 * 64 + lane];
            uint2 u1 = y2[(size_t)s1 * 64 + lane];
            a0 += bf_lo(u0.x) + bf_lo(u1.x);
            a1 += bf_hi(u0.x) + bf_hi(u1.x);
            a2 += bf_lo(u0.y) + bf_lo(u1.y);
            a3 += bf_hi(u0.y) + bf_hi(u1.y);
        }
        if (j < end) {
            uint2 u = y2[(size_t)col[j] * 64 + lane];
            a0 += bf_lo(u.x); a1 += bf_hi(u.x);
            a2 += bf_lo(u.y); a3 += bf_hi(u.y);
        }
        float dn = dis[n];
        out4[(size_t)n * 64 + lane] = make_float4(a0 * dn, a1 * dn, a2 * dn, a3 * dn);
    }
}

extern "C" void kernel_launch(void* const* d_in, const int* in_sizes, int n_in,
                              void* d_out, int out_size, void* d_ws, size_t ws_size,
                              hipStream_t stream) {
    const float* x = (const float*)d_in[0];
    const float* W = (const float*)d_in[1];
    const float* b = (const float*)d_in[2];
    const int* ei32 = (const int*)d_in[3];
    const long long* ei64 = (const long long*)d_in[3];
    const int N = in_sizes[0] / IN_DIM;
    const int E = in_sizes[3] / 2;
    const int MT = (N + 15) / 16;     // 16-row tiles
    float* out = (float*)d_out;

    char* ws = (char*)d_ws;
    size_t off = 0;
    auto alloc = [&](size_t bytes) -> void* {
        void* p = ws + off;
        off = (off + bytes + 255) & ~(size_t)255;
        return p;
    };
    __bf16* y    = (__bf16*)alloc((size_t)MT * 16 * OUT_DIM * sizeof(__bf16)); // 25.6 MB
    __bf16* Bh   = (__bf16*)alloc((size_t)IN_DIM * OUT_DIM * sizeof(__bf16));  // 256 KB
    __bf16* Bl   = (__bf16*)alloc((size_t)IN_DIM * OUT_DIM * sizeof(__bf16));
    float* dis   = (float*)alloc((size_t)N * sizeof(float));
    int*   cnt   = (int*)alloc((size_t)N * sizeof(int));
    int*   tmp   = (int*)alloc((size_t)N * sizeof(int));
    int*   rowptr= (int*)alloc((size_t)(N + 1) * sizeof(int));
    int*   cursor= (int*)alloc((size_t)N * sizeof(int));
    int*   bsum  = (int*)alloc(512 * sizeof(int));
    int*   bscan = (int*)alloc(512 * sizeof(int));
    int*   flag  = (int*)alloc(sizeof(int));
    int*   col   = (int*)alloc((size_t)E * sizeof(int));                       // 6.4 MB
    (void)ws_size; (void)n_in; (void)out_size;

    const int NB = (N + 255) >> 8;

    hipLaunchKernelGGL(detect_kernel, dim3(1), dim3(64), 0, stream, ei32, flag);
    hipLaunchKernelGGL(zero_i32, dim3((N + 255) / 256), dim3(256), 0, stream, cnt, N);
    hipLaunchKernelGGL(convert_w, dim3((OUT_DIM * (IN_DIM / 8) + 255) / 256), dim3(256), 0, stream, W, Bh, Bl);
    hipLaunchKernelGGL(count_kernel, dim3(2048), dim3(256), 0, stream, ei32, ei64, flag, cnt, E);
    hipLaunchKernelGGL(scan1_kernel, dim3(NB), dim3(256), 0, stream, cnt, tmp, bsum, N);
    hipLaunchKernelGGL(scan2_kernel, dim3(1), dim3(256), 0, stream, bsum, bscan, NB);
    hipLaunchKernelGGL(finalize_kernel, dim3((N + 255) / 256), dim3(256), 0, stream, tmp, bscan, cnt, rowptr, cursor, dis, N);
    hipLaunchKernelGGL(fill_kernel, dim3(2048), dim3(256), 0, stream, ei32, ei64, flag, cursor, col, E);
    hipLaunchKernelGGL(mfma_gemm, dim3((MT + 3) / 4), dim3(256), 0, stream,
                       x, Bh, Bl, b, dis, y, N, MT);
    hipLaunchKernelGGL(gather_kernel, dim3(2048), dim3(256), 0, stream,
                       (const uint2*)y, rowptr, col, dis, (float4*)out, N);
}